// Round 7
// baseline (4168.286 us; speedup 1.0000x reference)
//
#include <hip/hip_runtime.h>
#include <cstdint>
#include <cstddef>

// SNN_53618371723788: 2-layer SLSTM, B=65536, T=24, H=64, fp32.
// Pass 1: layer-1 recurrence, emits spike bitmasks + final mem1 to d_ws.
// Pass 2: layer-2 recurrence (union-shared ih) + extra step + Wout.
//
// R18: pass2 is LDS-issue-bound (R17 calibration: ~92% LDS pipe vs 46%
// VALU). Largest consumer: per-batch sparse ih reads (8 batches x ~16
// spiking rows = 128 ds_read_b128/wave-t of the SAME 64-row table; union
// coverage at r~0.25 is ~58/64 rows). Replace with ONE dense pass over all
// 64 Pih rows; per row, add into batches whose mask bit is set, gated by a
// wave-uniform SGPR bit test -> s_cbranch (SALU, co-issues with VALU; adds
// are skipped, not multiplied -- the R13 mistake). m-outer/j-inner
// ascending preserves each batch's exact add chain after the hh block ->
// absmax must stay 0.0. LDS: -64 reads/wave-t (-26% of pass2 demand).

#define BB 65536
#define TT 24
#define NB 8  // batch elements per wave

__device__ __forceinline__ float bcastf(float v, int l) {
  return __int_as_float(__builtin_amdgcn_readlane(__float_as_int(v), l));
}
__device__ __forceinline__ float sigm(float v) {
  return __fdividef(1.0f, 1.0f + __expf(-v));  // v_exp + v_rcp path
}
__device__ __forceinline__ float tanh_fast(float v) {
  // tanh(x) = 1 - 2/(e^{2x}+1); e^inf->inf, rcp(inf)->0 => saturates to +-1
  return fmaf(-2.0f, __fdividef(1.0f, __expf(2.0f * v) + 1.0f), 1.0f);
}
__device__ __forceinline__ float wsum(float v) {
#pragma unroll
  for (int o = 32; o > 0; o >>= 1) v += __shfl_xor(v, o);
  return v;
}

__global__ __attribute__((amdgpu_waves_per_eu(4, 4))) __launch_bounds__(512)
void snn_pass1(
    const float* __restrict__ x, const float* __restrict__ Wih1,
    const float* __restrict__ Whh1, const float* __restrict__ bih1,
    const float* __restrict__ bhh1, const float* __restrict__ thr1p,
    unsigned long long* __restrict__ spk_out, float* __restrict__ mem1_out) {
  // P1[m][j] = {Whh1[j][m], Whh1[64+j][m], Whh1[128+j][m], Whh1[192+j][m]}
  __shared__ float4 P1[64][64];     // 64 KB
  __shared__ float stM[8][64][NB];  // 16 KB -> 80 KB total, 2 blocks/CU
  int tid = threadIdx.x;
  int lane = tid & 63, wave = tid >> 6;
  int wb = (blockIdx.x * 8 + wave) * NB;  // first batch of this wave

  // preload this wave's entire x window: lane t holds x[b][t] (t<24)
  float xv[NB];
  int lt = (lane < TT) ? lane : (TT - 1);
#pragma unroll
  for (int b = 0; b < NB; b++) xv[b] = x[(size_t)(wb + b) * TT + lt];

  for (int idx = tid; idx < 16384; idx += 512) {
    int k = idx >> 6, m = idx & 63;
    ((float*)&P1[m][k & 63])[k >> 6] = Whh1[idx];
  }
  __syncthreads();
  float thr1 = thr1p[0];
  float b1q[4], wq[4];
#pragma unroll
  for (int q = 0; q < 4; q++) {
    b1q[q] = bih1[q * 64 + lane] + bhh1[q * 64 + lane];
    wq[q] = Wih1[q * 64 + lane];
  }
  float syn[NB], mem[NB];
#pragma unroll
  for (int b = 0; b < NB; b++) { syn[b] = 0.0f; mem[b] = 0.0f; }

  for (int t = 0; t < TT; t++) {
    // stage OLD mem state for this wave (per-wave strip, no barrier needed)
#pragma unroll
    for (int b = 0; b < NB; b++) stM[wave][lane][b] = mem[b];
    float acc[NB][4];
#pragma unroll
    for (int j = 0; j < NB; j++) {
      float xbt = bcastf(xv[j], t);  // v_readlane, no global load
#pragma unroll
      for (int q = 0; q < 4; q++) acc[j][q] = fmaf(xbt, wq[q], b1q[q]);
    }
    // single m-loop: weights read ONCE; state via LDS broadcast (cheap)
#pragma unroll 8
    for (int m = 0; m < 64; m++) {
      float4 w = P1[m][lane];                         // per-lane ds_read_b128
      float4 sa = *(const float4*)&stM[wave][m][0];   // broadcast j=0..3
      float4 sb = *(const float4*)&stM[wave][m][4];   // broadcast j=4..7
      float s[NB] = {sa.x, sa.y, sa.z, sa.w, sb.x, sb.y, sb.z, sb.w};
#pragma unroll
      for (int j = 0; j < NB; j++) {
        acc[j][0] = fmaf(s[j], w.x, acc[j][0]);
        acc[j][1] = fmaf(s[j], w.y, acc[j][1]);
        acc[j][2] = fmaf(s[j], w.z, acc[j][2]);
        acc[j][3] = fmaf(s[j], w.w, acc[j][3]);
      }
    }
    unsigned long long myspk = 0;  // lane b keeps batch b's ballot
#pragma unroll
    for (int j = 0; j < NB; j++) {
      float ig = sigm(acc[j][0]), fg = sigm(acc[j][1]);
      float gg = tanh_fast(acc[j][2]), og = sigm(acc[j][3]);
      float sn = fmaf(fg, syn[j], ig * gg);
      float rst = (mem[j] > thr1) ? thr1 : 0.0f;  // reset uses OLD mem
      float mn = fmaf(og, tanh_fast(sn), -rst);
      syn[j] = sn;
      mem[j] = mn;
      unsigned long long msk = __ballot(mn > thr1);  // wave-uniform
      if (lane == j) myspk = msk;
    }
    if (lane < NB)
      spk_out[(size_t)t * BB + wb + lane] = myspk;
  }
#pragma unroll
  for (int b = 0; b < NB; b++)
    mem1_out[(size_t)(wb + b) * 64 + lane] = mem[b];
}

__global__ __attribute__((amdgpu_waves_per_eu(4, 4))) __launch_bounds__(1024)
void snn_pass2(
    const float* __restrict__ Wih2, const float* __restrict__ Whh2,
    const float* __restrict__ bih2, const float* __restrict__ bhh2,
    const float* __restrict__ thr2p, const float* __restrict__ Wout,
    const float* __restrict__ bout,
    const unsigned long long* __restrict__ spk_in,
    const float* __restrict__ mem1_in, float* __restrict__ out) {
  __shared__ float4 Pih[64][64];     // 64 KB
  __shared__ float4 Phh[64][64];     // 64 KB
  __shared__ float stM[16][64][NB];  // 32 KB -> 160 KB total (1 block/CU)
  int tid = threadIdx.x;
  int lane = tid & 63, wave = tid >> 6;
  int wb = (blockIdx.x * 16 + wave) * NB;

  // prefetch t=0 spike masks before weight staging (latency under staging)
  unsigned long long raw[NB];
#pragma unroll
  for (int b = 0; b < NB; b++) raw[b] = spk_in[(size_t)0 * BB + wb + b];

  for (int idx = tid; idx < 16384; idx += 1024) {
    int k = idx >> 6, m = idx & 63;
    ((float*)&Pih[m][k & 63])[k >> 6] = Wih2[idx];
    ((float*)&Phh[m][k & 63])[k >> 6] = Whh2[idx];
  }
  __syncthreads();
  float thr2 = thr2p[0];
  float b2q[4];
#pragma unroll
  for (int q = 0; q < 4; q++) b2q[q] = bih2[q * 64 + lane] + bhh2[q * 64 + lane];
  float syn[NB], mem[NB];
  unsigned sb8[NB];  // per-lane spike history of THIS lane's neuron, bit t
#pragma unroll
  for (int b = 0; b < NB; b++) { syn[b] = 0.0f; mem[b] = 0.0f; sb8[b] = 0u; }

  for (int t = 0; t < TT; t++) {
    // consume prefetched masks -> SGPR u64 (wave-uniform)
    unsigned long long mk[NB];
#pragma unroll
    for (int b = 0; b < NB; b++) {
      unsigned lo = __builtin_amdgcn_readfirstlane((unsigned)raw[b]);
      unsigned hi = __builtin_amdgcn_readfirstlane((unsigned)(raw[b] >> 32));
      mk[b] = ((unsigned long long)hi << 32) | (unsigned long long)lo;
    }
    // issue next t's loads NOW; the compute below covers the latency
    if (t + 1 < TT) {
#pragma unroll
      for (int b = 0; b < NB; b++)
        raw[b] = spk_in[(size_t)(t + 1) * BB + wb + b];
    }
    // stage OLD mem2 state (per-wave strip)
#pragma unroll
    for (int b = 0; b < NB; b++) stM[wave][lane][b] = mem[b];
    float acc[NB][4];
#pragma unroll
    for (int j = 0; j < NB; j++) {
#pragma unroll
      for (int q = 0; q < 4; q++) acc[j][q] = b2q[q];
    }
    // dense hh: single m-loop, weights read ONCE, state via LDS broadcast
#pragma unroll 8
    for (int m = 0; m < 64; m++) {
      float4 wh = Phh[m][lane];                       // per-lane ds_read_b128
      float4 sa = *(const float4*)&stM[wave][m][0];   // broadcast j=0..3
      float4 sb = *(const float4*)&stM[wave][m][4];   // broadcast j=4..7
      float s[NB] = {sa.x, sa.y, sa.z, sa.w, sb.x, sb.y, sb.z, sb.w};
#pragma unroll
      for (int j = 0; j < NB; j++) {
        acc[j][0] = fmaf(s[j], wh.x, acc[j][0]);
        acc[j][1] = fmaf(s[j], wh.y, acc[j][1]);
        acc[j][2] = fmaf(s[j], wh.z, acc[j][2]);
        acc[j][3] = fmaf(s[j], wh.w, acc[j][3]);
      }
    }
    __builtin_amdgcn_sched_barrier(0);  // cap live-set before ih section
    // ih union pass: read each Pih row ONCE, add into batches whose bit is
    // set (wave-uniform SGPR test -> s_cbranch; adds skipped, not masked).
    // m-outer / j-inner ascending == each batch's old ascending-bit chain.
#pragma unroll 8
    for (int m = 0; m < 64; m++) {
      float4 r = Pih[m][lane];
#pragma unroll
      for (int j = 0; j < NB; j++) {
        if (mk[j] & (1ull << m)) {
          acc[j][0] += r.x; acc[j][1] += r.y;
          acc[j][2] += r.z; acc[j][3] += r.w;
        }
      }
    }
    // gates, per batch ascending (identical chain to R17)
#pragma unroll
    for (int j = 0; j < NB; j++) {
      float ig = sigm(acc[j][0]), fg = sigm(acc[j][1]);
      float gg = tanh_fast(acc[j][2]), og = sigm(acc[j][3]);
      float sn = fmaf(fg, syn[j], ig * gg);
      float rst = (mem[j] > thr2) ? thr2 : 0.0f;
      float mn = fmaf(og, tanh_fast(sn), -rst);
      syn[j] = sn;
      mem[j] = mn;
      sb8[j] |= (mn > thr2) ? (1u << t) : 0u;
    }
  }

  // extra step: input = final mem1 (dense). Keeps readlane form (4% of work).
  float m1[NB];
#pragma unroll
  for (int b = 0; b < NB; b++) m1[b] = mem1_in[(size_t)(wb + b) * 64 + lane];
  float acc[NB][4];
#pragma unroll
  for (int b = 0; b < NB; b++) {
#pragma unroll
    for (int q = 0; q < 4; q++) acc[b][q] = b2q[q];
  }
#pragma unroll 4
  for (int m = 0; m < 64; m++) {
    float4 wi = Pih[m][lane];
    float4 wh = Phh[m][lane];
#pragma unroll
    for (int b = 0; b < NB; b++) {
      float s1 = bcastf(m1[b], m);
      float s2 = bcastf(mem[b], m);
      acc[b][0] = fmaf(s1, wi.x, fmaf(s2, wh.x, acc[b][0]));
      acc[b][1] = fmaf(s1, wi.y, fmaf(s2, wh.y, acc[b][1]));
      acc[b][2] = fmaf(s1, wi.z, fmaf(s2, wh.z, acc[b][2]));
      acc[b][3] = fmaf(s1, wi.w, fmaf(s2, wh.w, acc[b][3]));
    }
  }
  // epilogue: replay p0/p1 accumulation (same fmaf order as before) from bits.
  float p0[NB], p1[NB];
#pragma unroll
  for (int b = 0; b < NB; b++) { p0[b] = 0.0f; p1[b] = 0.0f; }
#pragma unroll 4
  for (int t = 0; t < TT; t++) {
    float w0 = Wout[t * 64 + lane];
    float w1 = Wout[1664 + t * 64 + lane];
#pragma unroll
    for (int b = 0; b < NB; b++) {
      float sf = ((sb8[b] >> t) & 1u) ? 1.0f : 0.0f;
      p0[b] = fmaf(sf, w0, p0[b]);
      p1[b] = fmaf(sf, w1, p1[b]);
    }
  }
  float wA0 = Wout[1536 + lane], wA1 = Wout[1664 + 1536 + lane];  // spk2_last
  float wB0 = Wout[1600 + lane], wB1 = Wout[1664 + 1600 + lane];  // mem2 final
  float bo0 = bout[0], bo1 = bout[1];
#pragma unroll
  for (int b = 0; b < NB; b++) {
    float ig = sigm(acc[b][0]), fg = sigm(acc[b][1]);
    float gg = tanh_fast(acc[b][2]), og = sigm(acc[b][3]);
    float sn = fmaf(fg, syn[b], ig * gg);
    float rst = (mem[b] > thr2) ? thr2 : 0.0f;
    float mn = fmaf(og, tanh_fast(sn), -rst);
    float sf = (mn > thr2) ? 1.0f : 0.0f;
    p0[b] = fmaf(sf, wA0, p0[b]);
    p1[b] = fmaf(sf, wA1, p1[b]);
    p0[b] = fmaf(mn, wB0, p0[b]);
    p1[b] = fmaf(mn, wB1, p1[b]);
  }
  // cross-lane reduce; wsum result is uniform, keep own lane's value.
  float vout = 0.0f;
#pragma unroll
  for (int b = 0; b < NB; b++) {
    float r0 = wsum(p0[b]);
    float r1 = wsum(p1[b]);
    if (lane == 2 * b) vout = r0;
    if (lane == 2 * b + 1) vout = r1;
  }
  if (lane < 2 * NB)
    out[(size_t)wb * 2 + lane] = vout + ((lane & 1) ? bo1 : bo0);
}

extern "C" void kernel_launch(void* const* d_in, const int* in_sizes, int n_in,
                              void* d_out, int out_size, void* d_ws, size_t ws_size,
                              hipStream_t stream) {
  const float* x = (const float*)d_in[0];
  const float* Wih1 = (const float*)d_in[1];
  const float* Whh1 = (const float*)d_in[2];
  const float* bih1 = (const float*)d_in[3];
  const float* bhh1 = (const float*)d_in[4];
  const float* thr1 = (const float*)d_in[5];
  const float* Wih2 = (const float*)d_in[6];
  const float* Whh2 = (const float*)d_in[7];
  const float* bih2 = (const float*)d_in[8];
  const float* bhh2 = (const float*)d_in[9];
  const float* thr2 = (const float*)d_in[10];
  const float* Wout = (const float*)d_in[11];
  const float* bout = (const float*)d_in[12];

  unsigned long long* spk = (unsigned long long*)d_ws;
  float* mem1 = (float*)((char*)d_ws + (size_t)TT * BB * 8);

  snn_pass1<<<BB / (8 * NB), 512, 0, stream>>>(x, Wih1, Whh1, bih1, bhh1, thr1,
                                               spk, mem1);
  snn_pass2<<<BB / (16 * NB), 1024, 0, stream>>>(Wih2, Whh2, bih2, bhh2, thr2,
                                                 Wout, bout, spk, mem1,
                                                 (float*)d_out);
}

// Round 8
// 1966.901 us; speedup vs baseline: 2.1192x; 2.1192x over previous
//
#include <hip/hip_runtime.h>
#include <cstdint>
#include <cstddef>

// SNN_53618371723788: 2-layer SLSTM, B=65536, T=24, H=64, fp32.
// Pass 1: layer-1 recurrence, emits spike bitmasks + final mem1 to d_ws.
// Pass 2: layer-2 recurrence (sparse ih via spike masks) + extra step + Wout.
//
// R19 (base = R17, the 1718us frontier; R18's union-branch pass reverted --
// 512 wave-uniform branches cost far more than 64 saved LDS reads):
//  - pass1: NB=16 (512 thr, 8 waves, 128 batch/block). Halves total hh
//    weight ds_read_b128 (the only LDS term that scales with wave count;
//    floor 465->343us). stM padded [20]: 8-way instead of 32-way write
//    conflicts, rows stay 16B-aligned. 104KB LDS -> 1 block/CU, 2 w/SIMD.
//  - pass2: R17 + Phh rows 0..11 cached in 48 VGPRs (static unroll);
//    weight reads 64->52 per wave-t. Else byte-identical.
// Per-batch fmaf chains unchanged (ascending m, same gate order) ->
// absmax must stay 0.0.

#define BB 65536
#define TT 24
#define NB 8    // pass2 batches per wave
#define NB1 16  // pass1 batches per wave

__device__ __forceinline__ float bcastf(float v, int l) {
  return __int_as_float(__builtin_amdgcn_readlane(__float_as_int(v), l));
}
__device__ __forceinline__ float sigm(float v) {
  return __fdividef(1.0f, 1.0f + __expf(-v));  // v_exp + v_rcp path
}
__device__ __forceinline__ float tanh_fast(float v) {
  // tanh(x) = 1 - 2/(e^{2x}+1); e^inf->inf, rcp(inf)->0 => saturates to +-1
  return fmaf(-2.0f, __fdividef(1.0f, __expf(2.0f * v) + 1.0f), 1.0f);
}
__device__ __forceinline__ float wsum(float v) {
#pragma unroll
  for (int o = 32; o > 0; o >>= 1) v += __shfl_xor(v, o);
  return v;
}

__global__ __attribute__((amdgpu_waves_per_eu(2, 2))) __launch_bounds__(512)
void snn_pass1(
    const float* __restrict__ x, const float* __restrict__ Wih1,
    const float* __restrict__ Whh1, const float* __restrict__ bih1,
    const float* __restrict__ bhh1, const float* __restrict__ thr1p,
    unsigned long long* __restrict__ spk_out, float* __restrict__ mem1_out) {
  // P1[m][j] = {Whh1[j][m], Whh1[64+j][m], Whh1[128+j][m], Whh1[192+j][m]}
  __shared__ float4 P1[64][64];     // 64 KB
  __shared__ float stM[8][64][20];  // 40 KB (pad 16->20: 8-way, 16B-aligned)
  int tid = threadIdx.x;
  int lane = tid & 63, wave = tid >> 6;
  int wb = (blockIdx.x * 8 + wave) * NB1;  // first batch of this wave

  // preload this wave's entire x window: lane t holds x[b][t] (t<24)
  float xv[NB1];
  int lt = (lane < TT) ? lane : (TT - 1);
#pragma unroll
  for (int b = 0; b < NB1; b++) xv[b] = x[(size_t)(wb + b) * TT + lt];

  for (int idx = tid; idx < 16384; idx += 512) {
    int k = idx >> 6, m = idx & 63;
    ((float*)&P1[m][k & 63])[k >> 6] = Whh1[idx];
  }
  __syncthreads();
  float thr1 = thr1p[0];
  float b1q[4], wq[4];
#pragma unroll
  for (int q = 0; q < 4; q++) {
    b1q[q] = bih1[q * 64 + lane] + bhh1[q * 64 + lane];
    wq[q] = Wih1[q * 64 + lane];
  }
  float syn[NB1], mem[NB1];
#pragma unroll
  for (int b = 0; b < NB1; b++) { syn[b] = 0.0f; mem[b] = 0.0f; }

  for (int t = 0; t < TT; t++) {
    // stage OLD mem state (per-wave strip, same-wave write->read, no barrier)
#pragma unroll
    for (int b = 0; b < NB1; b++) stM[wave][lane][b] = mem[b];
    float acc[NB1][4];
#pragma unroll
    for (int j = 0; j < NB1; j++) {
      float xbt = bcastf(xv[j], t);  // v_readlane, no global load
#pragma unroll
      for (int q = 0; q < 4; q++) acc[j][q] = fmaf(xbt, wq[q], b1q[q]);
    }
    // single m-loop: weights read ONCE per 16 batches; state via LDS bcast
#pragma unroll 8
    for (int m = 0; m < 64; m++) {
      float4 w = P1[m][lane];  // per-lane ds_read_b128 (conflict-free)
      const float4* srow = (const float4*)&stM[wave][m][0];
      float4 sa = srow[0], sb = srow[1], sc = srow[2], sd = srow[3];
      float s[NB1] = {sa.x, sa.y, sa.z, sa.w, sb.x, sb.y, sb.z, sb.w,
                      sc.x, sc.y, sc.z, sc.w, sd.x, sd.y, sd.z, sd.w};
#pragma unroll
      for (int j = 0; j < NB1; j++) {
        acc[j][0] = fmaf(s[j], w.x, acc[j][0]);
        acc[j][1] = fmaf(s[j], w.y, acc[j][1]);
        acc[j][2] = fmaf(s[j], w.z, acc[j][2]);
        acc[j][3] = fmaf(s[j], w.w, acc[j][3]);
      }
    }
    unsigned long long myspk = 0;  // lane b keeps batch b's ballot
#pragma unroll
    for (int j = 0; j < NB1; j++) {
      float ig = sigm(acc[j][0]), fg = sigm(acc[j][1]);
      float gg = tanh_fast(acc[j][2]), og = sigm(acc[j][3]);
      float sn = fmaf(fg, syn[j], ig * gg);
      float rst = (mem[j] > thr1) ? thr1 : 0.0f;  // reset uses OLD mem
      float mn = fmaf(og, tanh_fast(sn), -rst);
      syn[j] = sn;
      mem[j] = mn;
      unsigned long long msk = __ballot(mn > thr1);  // wave-uniform
      if (lane == j) myspk = msk;
    }
    if (lane < NB1)
      spk_out[(size_t)t * BB + wb + lane] = myspk;
  }
#pragma unroll
  for (int b = 0; b < NB1; b++)
    mem1_out[(size_t)(wb + b) * 64 + lane] = mem[b];
}

__global__ __attribute__((amdgpu_waves_per_eu(4, 4))) __launch_bounds__(1024)
void snn_pass2(
    const float* __restrict__ Wih2, const float* __restrict__ Whh2,
    const float* __restrict__ bih2, const float* __restrict__ bhh2,
    const float* __restrict__ thr2p, const float* __restrict__ Wout,
    const float* __restrict__ bout,
    const unsigned long long* __restrict__ spk_in,
    const float* __restrict__ mem1_in, float* __restrict__ out) {
  __shared__ float4 Pih[64][64];     // 64 KB
  __shared__ float4 Phh[64][64];     // 64 KB
  __shared__ float stM[16][64][NB];  // 32 KB -> 160 KB total (1 block/CU)
  int tid = threadIdx.x;
  int lane = tid & 63, wave = tid >> 6;
  int wb = (blockIdx.x * 16 + wave) * NB;

  // prefetch t=0 spike masks before weight staging (latency under staging)
  unsigned long long raw[NB];
#pragma unroll
  for (int b = 0; b < NB; b++) raw[b] = spk_in[(size_t)0 * BB + wb + b];

  for (int idx = tid; idx < 16384; idx += 1024) {
    int k = idx >> 6, m = idx & 63;
    ((float*)&Pih[m][k & 63])[k >> 6] = Wih2[idx];
    ((float*)&Phh[m][k & 63])[k >> 6] = Whh2[idx];
  }
  __syncthreads();
  // register-cache the first 12 Phh rows (static indexing -> stays in VGPRs)
  float4 whreg[12];
#pragma unroll
  for (int r = 0; r < 12; r++) whreg[r] = Phh[r][lane];
  float thr2 = thr2p[0];
  float b2q[4];
#pragma unroll
  for (int q = 0; q < 4; q++) b2q[q] = bih2[q * 64 + lane] + bhh2[q * 64 + lane];
  float syn[NB], mem[NB];
  unsigned sb8[NB];  // per-lane spike history of THIS lane's neuron, bit t
#pragma unroll
  for (int b = 0; b < NB; b++) { syn[b] = 0.0f; mem[b] = 0.0f; sb8[b] = 0u; }

  for (int t = 0; t < TT; t++) {
    // consume prefetched masks -> SGPR u64 (wave-uniform)
    unsigned long long mk[NB];
#pragma unroll
    for (int b = 0; b < NB; b++) {
      unsigned lo = __builtin_amdgcn_readfirstlane((unsigned)raw[b]);
      unsigned hi = __builtin_amdgcn_readfirstlane((unsigned)(raw[b] >> 32));
      mk[b] = ((unsigned long long)hi << 32) | (unsigned long long)lo;
    }
    // issue next t's loads NOW; the compute below covers the latency
    if (t + 1 < TT) {
#pragma unroll
      for (int b = 0; b < NB; b++)
        raw[b] = spk_in[(size_t)(t + 1) * BB + wb + b];
    }
    // stage OLD mem2 state (per-wave strip)
#pragma unroll
    for (int b = 0; b < NB; b++) stM[wave][lane][b] = mem[b];
    float acc[NB][4];
#pragma unroll
    for (int j = 0; j < NB; j++) {
#pragma unroll
      for (int q = 0; q < 4; q++) acc[j][q] = b2q[q];
    }
    // dense hh, rows 0..11 from registers (no LDS weight read)
#pragma unroll
    for (int m = 0; m < 12; m++) {
      float4 wh = whreg[m];
      float4 sa = *(const float4*)&stM[wave][m][0];   // broadcast j=0..3
      float4 sb = *(const float4*)&stM[wave][m][4];   // broadcast j=4..7
      float s[NB] = {sa.x, sa.y, sa.z, sa.w, sb.x, sb.y, sb.z, sb.w};
#pragma unroll
      for (int j = 0; j < NB; j++) {
        acc[j][0] = fmaf(s[j], wh.x, acc[j][0]);
        acc[j][1] = fmaf(s[j], wh.y, acc[j][1]);
        acc[j][2] = fmaf(s[j], wh.z, acc[j][2]);
        acc[j][3] = fmaf(s[j], wh.w, acc[j][3]);
      }
    }
    // dense hh, rows 12..63 from LDS
#pragma unroll 8
    for (int m = 12; m < 64; m++) {
      float4 wh = Phh[m][lane];                       // per-lane ds_read_b128
      float4 sa = *(const float4*)&stM[wave][m][0];   // broadcast j=0..3
      float4 sb = *(const float4*)&stM[wave][m][4];   // broadcast j=4..7
      float s[NB] = {sa.x, sa.y, sa.z, sa.w, sb.x, sb.y, sb.z, sb.w};
#pragma unroll
      for (int j = 0; j < NB; j++) {
        acc[j][0] = fmaf(s[j], wh.x, acc[j][0]);
        acc[j][1] = fmaf(s[j], wh.y, acc[j][1]);
        acc[j][2] = fmaf(s[j], wh.z, acc[j][2]);
        acc[j][3] = fmaf(s[j], wh.w, acc[j][3]);
      }
    }
    __builtin_amdgcn_sched_barrier(0);  // cap live-set before sparse section
    // sparse ih + gates, per batch ascending (identical chain to R17)
#pragma unroll
    for (int j = 0; j < NB; j++) {
      unsigned long long k = mk[j];
      while (__builtin_popcountll(k) >= 4) {
        int m0 = __builtin_ctzll(k); k &= k - 1;
        int m1 = __builtin_ctzll(k); k &= k - 1;
        int m2 = __builtin_ctzll(k); k &= k - 1;
        int m3 = __builtin_ctzll(k); k &= k - 1;
        float4 r0 = Pih[m0][lane];
        float4 r1 = Pih[m1][lane];
        float4 r2 = Pih[m2][lane];
        float4 r3 = Pih[m3][lane];  // 4 reads in flight before first consume
        acc[j][0] += r0.x; acc[j][1] += r0.y; acc[j][2] += r0.z; acc[j][3] += r0.w;
        acc[j][0] += r1.x; acc[j][1] += r1.y; acc[j][2] += r1.z; acc[j][3] += r1.w;
        acc[j][0] += r2.x; acc[j][1] += r2.y; acc[j][2] += r2.z; acc[j][3] += r2.w;
        acc[j][0] += r3.x; acc[j][1] += r3.y; acc[j][2] += r3.z; acc[j][3] += r3.w;
      }
      while (k) {
        int m0 = __builtin_ctzll(k); k &= k - 1;
        float4 r0 = Pih[m0][lane];
        acc[j][0] += r0.x; acc[j][1] += r0.y; acc[j][2] += r0.z; acc[j][3] += r0.w;
      }
      float ig = sigm(acc[j][0]), fg = sigm(acc[j][1]);
      float gg = tanh_fast(acc[j][2]), og = sigm(acc[j][3]);
      float sn = fmaf(fg, syn[j], ig * gg);
      float rst = (mem[j] > thr2) ? thr2 : 0.0f;
      float mn = fmaf(og, tanh_fast(sn), -rst);
      syn[j] = sn;
      mem[j] = mn;
      sb8[j] |= (mn > thr2) ? (1u << t) : 0u;
    }
  }

  // extra step: input = final mem1 (dense). Keeps readlane form (4% of work).
  float m1[NB];
#pragma unroll
  for (int b = 0; b < NB; b++) m1[b] = mem1_in[(size_t)(wb + b) * 64 + lane];
  float acc[NB][4];
#pragma unroll
  for (int b = 0; b < NB; b++) {
#pragma unroll
    for (int q = 0; q < 4; q++) acc[b][q] = b2q[q];
  }
#pragma unroll 4
  for (int m = 0; m < 64; m++) {
    float4 wi = Pih[m][lane];
    float4 wh = Phh[m][lane];
#pragma unroll
    for (int b = 0; b < NB; b++) {
      float s1 = bcastf(m1[b], m);
      float s2 = bcastf(mem[b], m);
      acc[b][0] = fmaf(s1, wi.x, fmaf(s2, wh.x, acc[b][0]));
      acc[b][1] = fmaf(s1, wi.y, fmaf(s2, wh.y, acc[b][1]));
      acc[b][2] = fmaf(s1, wi.z, fmaf(s2, wh.z, acc[b][2]));
      acc[b][3] = fmaf(s1, wi.w, fmaf(s2, wh.w, acc[b][3]));
    }
  }
  // epilogue: replay p0/p1 accumulation (same fmaf order as before) from bits.
  float p0[NB], p1[NB];
#pragma unroll
  for (int b = 0; b < NB; b++) { p0[b] = 0.0f; p1[b] = 0.0f; }
#pragma unroll 4
  for (int t = 0; t < TT; t++) {
    float w0 = Wout[t * 64 + lane];
    float w1 = Wout[1664 + t * 64 + lane];
#pragma unroll
    for (int b = 0; b < NB; b++) {
      float sf = ((sb8[b] >> t) & 1u) ? 1.0f : 0.0f;
      p0[b] = fmaf(sf, w0, p0[b]);
      p1[b] = fmaf(sf, w1, p1[b]);
    }
  }
  float wA0 = Wout[1536 + lane], wA1 = Wout[1664 + 1536 + lane];  // spk2_last
  float wB0 = Wout[1600 + lane], wB1 = Wout[1664 + 1600 + lane];  // mem2 final
  float bo0 = bout[0], bo1 = bout[1];
#pragma unroll
  for (int b = 0; b < NB; b++) {
    float ig = sigm(acc[b][0]), fg = sigm(acc[b][1]);
    float gg = tanh_fast(acc[b][2]), og = sigm(acc[b][3]);
    float sn = fmaf(fg, syn[b], ig * gg);
    float rst = (mem[b] > thr2) ? thr2 : 0.0f;
    float mn = fmaf(og, tanh_fast(sn), -rst);
    float sf = (mn > thr2) ? 1.0f : 0.0f;
    p0[b] = fmaf(sf, wA0, p0[b]);
    p1[b] = fmaf(sf, wA1, p1[b]);
    p0[b] = fmaf(mn, wB0, p0[b]);
    p1[b] = fmaf(mn, wB1, p1[b]);
  }
  // cross-lane reduce; wsum result is uniform, keep own lane's value.
  float vout = 0.0f;
#pragma unroll
  for (int b = 0; b < NB; b++) {
    float r0 = wsum(p0[b]);
    float r1 = wsum(p1[b]);
    if (lane == 2 * b) vout = r0;
    if (lane == 2 * b + 1) vout = r1;
  }
  if (lane < 2 * NB)
    out[(size_t)wb * 2 + lane] = vout + ((lane & 1) ? bo1 : bo0);
}

extern "C" void kernel_launch(void* const* d_in, const int* in_sizes, int n_in,
                              void* d_out, int out_size, void* d_ws, size_t ws_size,
                              hipStream_t stream) {
  const float* x = (const float*)d_in[0];
  const float* Wih1 = (const float*)d_in[1];
  const float* Whh1 = (const float*)d_in[2];
  const float* bih1 = (const float*)d_in[3];
  const float* bhh1 = (const float*)d_in[4];
  const float* thr1 = (const float*)d_in[5];
  const float* Wih2 = (const float*)d_in[6];
  const float* Whh2 = (const float*)d_in[7];
  const float* bih2 = (const float*)d_in[8];
  const float* bhh2 = (const float*)d_in[9];
  const float* thr2 = (const float*)d_in[10];
  const float* Wout = (const float*)d_in[11];
  const float* bout = (const float*)d_in[12];

  unsigned long long* spk = (unsigned long long*)d_ws;
  float* mem1 = (float*)((char*)d_ws + (size_t)TT * BB * 8);

  snn_pass1<<<BB / (8 * NB1), 512, 0, stream>>>(x, Wih1, Whh1, bih1, bhh1,
                                                thr1, spk, mem1);
  snn_pass2<<<BB / (16 * NB), 1024, 0, stream>>>(Wih2, Whh2, bih2, bhh2, thr2,
                                                 Wout, bout, spk, mem1,
                                                 (float*)d_out);
}

// Round 9
// 1714.376 us; speedup vs baseline: 2.4314x; 1.1473x over previous
//
#include <hip/hip_runtime.h>
#include <cstdint>
#include <cstddef>

// SNN_53618371723788: 2-layer SLSTM, B=65536, T=24, H=64, fp32.
// Pass 1: layer-1 recurrence, emits spike bitmasks + final mem1 to d_ws.
// Pass 2: layer-2 recurrence (sparse ih via spike masks) + extra step + Wout.
//
// R20: exact restore of R17, the measured frontier (1718us). R19's two
// changes both regressed: (a) pass2 whreg[12] reg-cache spilled to scratch
// (FETCH 15MB->1.64GB, WRITE->2.2GB -- scratch traffic at 39% HBM peak),
// (b) pass1 NB=16 halved weight reads but cost occupancy (2 waves/SIMD,
// lost latency cover). Ledger R13-R19: LDS work cannot profitably move to
// VALU-FMA (R13), readlane (R16), scalar branch (R18), registers (R19),
// or L2 (R15). Pass2 runs at ~92% of its LDS-issue floor; R17 structure
// is locally optimal. absmax must stay 0.0 (identical arithmetic).

#define BB 65536
#define TT 24
#define NB 8  // batch elements per wave

__device__ __forceinline__ float bcastf(float v, int l) {
  return __int_as_float(__builtin_amdgcn_readlane(__float_as_int(v), l));
}
__device__ __forceinline__ float sigm(float v) {
  return __fdividef(1.0f, 1.0f + __expf(-v));  // v_exp + v_rcp path
}
__device__ __forceinline__ float tanh_fast(float v) {
  // tanh(x) = 1 - 2/(e^{2x}+1); e^inf->inf, rcp(inf)->0 => saturates to +-1
  return fmaf(-2.0f, __fdividef(1.0f, __expf(2.0f * v) + 1.0f), 1.0f);
}
__device__ __forceinline__ float wsum(float v) {
#pragma unroll
  for (int o = 32; o > 0; o >>= 1) v += __shfl_xor(v, o);
  return v;
}

__global__ __attribute__((amdgpu_waves_per_eu(4, 4))) __launch_bounds__(512)
void snn_pass1(
    const float* __restrict__ x, const float* __restrict__ Wih1,
    const float* __restrict__ Whh1, const float* __restrict__ bih1,
    const float* __restrict__ bhh1, const float* __restrict__ thr1p,
    unsigned long long* __restrict__ spk_out, float* __restrict__ mem1_out) {
  // P1[m][j] = {Whh1[j][m], Whh1[64+j][m], Whh1[128+j][m], Whh1[192+j][m]}
  __shared__ float4 P1[64][64];     // 64 KB
  __shared__ float stM[8][64][NB];  // 16 KB -> 80 KB total, 2 blocks/CU
  int tid = threadIdx.x;
  int lane = tid & 63, wave = tid >> 6;
  int wb = (blockIdx.x * 8 + wave) * NB;  // first batch of this wave

  // preload this wave's entire x window: lane t holds x[b][t] (t<24)
  float xv[NB];
  int lt = (lane < TT) ? lane : (TT - 1);
#pragma unroll
  for (int b = 0; b < NB; b++) xv[b] = x[(size_t)(wb + b) * TT + lt];

  for (int idx = tid; idx < 16384; idx += 512) {
    int k = idx >> 6, m = idx & 63;
    ((float*)&P1[m][k & 63])[k >> 6] = Whh1[idx];
  }
  __syncthreads();
  float thr1 = thr1p[0];
  float b1q[4], wq[4];
#pragma unroll
  for (int q = 0; q < 4; q++) {
    b1q[q] = bih1[q * 64 + lane] + bhh1[q * 64 + lane];
    wq[q] = Wih1[q * 64 + lane];
  }
  float syn[NB], mem[NB];
#pragma unroll
  for (int b = 0; b < NB; b++) { syn[b] = 0.0f; mem[b] = 0.0f; }

  for (int t = 0; t < TT; t++) {
    // stage OLD mem state for this wave (per-wave strip, no barrier needed)
#pragma unroll
    for (int b = 0; b < NB; b++) stM[wave][lane][b] = mem[b];
    float acc[NB][4];
#pragma unroll
    for (int j = 0; j < NB; j++) {
      float xbt = bcastf(xv[j], t);  // v_readlane, no global load
#pragma unroll
      for (int q = 0; q < 4; q++) acc[j][q] = fmaf(xbt, wq[q], b1q[q]);
    }
    // single m-loop: weights read ONCE; state via LDS broadcast (cheap)
#pragma unroll 8
    for (int m = 0; m < 64; m++) {
      float4 w = P1[m][lane];                         // per-lane ds_read_b128
      float4 sa = *(const float4*)&stM[wave][m][0];   // broadcast j=0..3
      float4 sb = *(const float4*)&stM[wave][m][4];   // broadcast j=4..7
      float s[NB] = {sa.x, sa.y, sa.z, sa.w, sb.x, sb.y, sb.z, sb.w};
#pragma unroll
      for (int j = 0; j < NB; j++) {
        acc[j][0] = fmaf(s[j], w.x, acc[j][0]);
        acc[j][1] = fmaf(s[j], w.y, acc[j][1]);
        acc[j][2] = fmaf(s[j], w.z, acc[j][2]);
        acc[j][3] = fmaf(s[j], w.w, acc[j][3]);
      }
    }
    unsigned long long myspk = 0;  // lane b keeps batch b's ballot
#pragma unroll
    for (int j = 0; j < NB; j++) {
      float ig = sigm(acc[j][0]), fg = sigm(acc[j][1]);
      float gg = tanh_fast(acc[j][2]), og = sigm(acc[j][3]);
      float sn = fmaf(fg, syn[j], ig * gg);
      float rst = (mem[j] > thr1) ? thr1 : 0.0f;  // reset uses OLD mem
      float mn = fmaf(og, tanh_fast(sn), -rst);
      syn[j] = sn;
      mem[j] = mn;
      unsigned long long msk = __ballot(mn > thr1);  // wave-uniform
      if (lane == j) myspk = msk;
    }
    if (lane < NB)
      spk_out[(size_t)t * BB + wb + lane] = myspk;
  }
#pragma unroll
  for (int b = 0; b < NB; b++)
    mem1_out[(size_t)(wb + b) * 64 + lane] = mem[b];
}

__global__ __attribute__((amdgpu_waves_per_eu(4, 4))) __launch_bounds__(1024)
void snn_pass2(
    const float* __restrict__ Wih2, const float* __restrict__ Whh2,
    const float* __restrict__ bih2, const float* __restrict__ bhh2,
    const float* __restrict__ thr2p, const float* __restrict__ Wout,
    const float* __restrict__ bout,
    const unsigned long long* __restrict__ spk_in,
    const float* __restrict__ mem1_in, float* __restrict__ out) {
  __shared__ float4 Pih[64][64];     // 64 KB
  __shared__ float4 Phh[64][64];     // 64 KB
  __shared__ float stM[16][64][NB];  // 32 KB -> 160 KB total (1 block/CU)
  int tid = threadIdx.x;
  int lane = tid & 63, wave = tid >> 6;
  int wb = (blockIdx.x * 16 + wave) * NB;

  // prefetch t=0 spike masks before weight staging (latency under staging)
  unsigned long long raw[NB];
#pragma unroll
  for (int b = 0; b < NB; b++) raw[b] = spk_in[(size_t)0 * BB + wb + b];

  for (int idx = tid; idx < 16384; idx += 1024) {
    int k = idx >> 6, m = idx & 63;
    ((float*)&Pih[m][k & 63])[k >> 6] = Wih2[idx];
    ((float*)&Phh[m][k & 63])[k >> 6] = Whh2[idx];
  }
  __syncthreads();
  float thr2 = thr2p[0];
  float b2q[4];
#pragma unroll
  for (int q = 0; q < 4; q++) b2q[q] = bih2[q * 64 + lane] + bhh2[q * 64 + lane];
  float syn[NB], mem[NB];
  unsigned sb8[NB];  // per-lane spike history of THIS lane's neuron, bit t
#pragma unroll
  for (int b = 0; b < NB; b++) { syn[b] = 0.0f; mem[b] = 0.0f; sb8[b] = 0u; }

  for (int t = 0; t < TT; t++) {
    // consume prefetched masks -> SGPR u64 (wave-uniform)
    unsigned long long mk[NB];
#pragma unroll
    for (int b = 0; b < NB; b++) {
      unsigned lo = __builtin_amdgcn_readfirstlane((unsigned)raw[b]);
      unsigned hi = __builtin_amdgcn_readfirstlane((unsigned)(raw[b] >> 32));
      mk[b] = ((unsigned long long)hi << 32) | (unsigned long long)lo;
    }
    // issue next t's loads NOW; the compute below covers the latency
    if (t + 1 < TT) {
#pragma unroll
      for (int b = 0; b < NB; b++)
        raw[b] = spk_in[(size_t)(t + 1) * BB + wb + b];
    }
    // stage OLD mem2 state (per-wave strip)
#pragma unroll
    for (int b = 0; b < NB; b++) stM[wave][lane][b] = mem[b];
    float acc[NB][4];
#pragma unroll
    for (int j = 0; j < NB; j++) {
#pragma unroll
      for (int q = 0; q < 4; q++) acc[j][q] = b2q[q];
    }
    // dense hh: single m-loop, weights read ONCE, state via LDS broadcast
#pragma unroll 8
    for (int m = 0; m < 64; m++) {
      float4 wh = Phh[m][lane];                       // per-lane ds_read_b128
      float4 sa = *(const float4*)&stM[wave][m][0];   // broadcast j=0..3
      float4 sb = *(const float4*)&stM[wave][m][4];   // broadcast j=4..7
      float s[NB] = {sa.x, sa.y, sa.z, sa.w, sb.x, sb.y, sb.z, sb.w};
#pragma unroll
      for (int j = 0; j < NB; j++) {
        acc[j][0] = fmaf(s[j], wh.x, acc[j][0]);
        acc[j][1] = fmaf(s[j], wh.y, acc[j][1]);
        acc[j][2] = fmaf(s[j], wh.z, acc[j][2]);
        acc[j][3] = fmaf(s[j], wh.w, acc[j][3]);
      }
    }
    __builtin_amdgcn_sched_barrier(0);  // cap live-set before sparse section
    // sparse ih + gates, per batch ascending (identical chain to R14)
#pragma unroll
    for (int j = 0; j < NB; j++) {
      unsigned long long k = mk[j];
      while (__builtin_popcountll(k) >= 4) {
        int m0 = __builtin_ctzll(k); k &= k - 1;
        int m1 = __builtin_ctzll(k); k &= k - 1;
        int m2 = __builtin_ctzll(k); k &= k - 1;
        int m3 = __builtin_ctzll(k); k &= k - 1;
        float4 r0 = Pih[m0][lane];
        float4 r1 = Pih[m1][lane];
        float4 r2 = Pih[m2][lane];
        float4 r3 = Pih[m3][lane];  // 4 reads in flight before first consume
        acc[j][0] += r0.x; acc[j][1] += r0.y; acc[j][2] += r0.z; acc[j][3] += r0.w;
        acc[j][0] += r1.x; acc[j][1] += r1.y; acc[j][2] += r1.z; acc[j][3] += r1.w;
        acc[j][0] += r2.x; acc[j][1] += r2.y; acc[j][2] += r2.z; acc[j][3] += r2.w;
        acc[j][0] += r3.x; acc[j][1] += r3.y; acc[j][2] += r3.z; acc[j][3] += r3.w;
      }
      while (k) {
        int m0 = __builtin_ctzll(k); k &= k - 1;
        float4 r0 = Pih[m0][lane];
        acc[j][0] += r0.x; acc[j][1] += r0.y; acc[j][2] += r0.z; acc[j][3] += r0.w;
      }
      float ig = sigm(acc[j][0]), fg = sigm(acc[j][1]);
      float gg = tanh_fast(acc[j][2]), og = sigm(acc[j][3]);
      float sn = fmaf(fg, syn[j], ig * gg);
      float rst = (mem[j] > thr2) ? thr2 : 0.0f;
      float mn = fmaf(og, tanh_fast(sn), -rst);
      syn[j] = sn;
      mem[j] = mn;
      sb8[j] |= (mn > thr2) ? (1u << t) : 0u;
    }
  }

  // extra step: input = final mem1 (dense). Keeps readlane form (4% of work).
  float m1[NB];
#pragma unroll
  for (int b = 0; b < NB; b++) m1[b] = mem1_in[(size_t)(wb + b) * 64 + lane];
  float acc[NB][4];
#pragma unroll
  for (int b = 0; b < NB; b++) {
#pragma unroll
    for (int q = 0; q < 4; q++) acc[b][q] = b2q[q];
  }
#pragma unroll 4
  for (int m = 0; m < 64; m++) {
    float4 wi = Pih[m][lane];
    float4 wh = Phh[m][lane];
#pragma unroll
    for (int b = 0; b < NB; b++) {
      float s1 = bcastf(m1[b], m);
      float s2 = bcastf(mem[b], m);
      acc[b][0] = fmaf(s1, wi.x, fmaf(s2, wh.x, acc[b][0]));
      acc[b][1] = fmaf(s1, wi.y, fmaf(s2, wh.y, acc[b][1]));
      acc[b][2] = fmaf(s1, wi.z, fmaf(s2, wh.z, acc[b][2]));
      acc[b][3] = fmaf(s1, wi.w, fmaf(s2, wh.w, acc[b][3]));
    }
  }
  // epilogue: replay p0/p1 accumulation (same fmaf order as before) from bits.
  float p0[NB], p1[NB];
#pragma unroll
  for (int b = 0; b < NB; b++) { p0[b] = 0.0f; p1[b] = 0.0f; }
#pragma unroll 4
  for (int t = 0; t < TT; t++) {
    float w0 = Wout[t * 64 + lane];
    float w1 = Wout[1664 + t * 64 + lane];
#pragma unroll
    for (int b = 0; b < NB; b++) {
      float sf = ((sb8[b] >> t) & 1u) ? 1.0f : 0.0f;
      p0[b] = fmaf(sf, w0, p0[b]);
      p1[b] = fmaf(sf, w1, p1[b]);
    }
  }
  float wA0 = Wout[1536 + lane], wA1 = Wout[1664 + 1536 + lane];  // spk2_last
  float wB0 = Wout[1600 + lane], wB1 = Wout[1664 + 1600 + lane];  // mem2 final
  float bo0 = bout[0], bo1 = bout[1];
#pragma unroll
  for (int b = 0; b < NB; b++) {
    float ig = sigm(acc[b][0]), fg = sigm(acc[b][1]);
    float gg = tanh_fast(acc[b][2]), og = sigm(acc[b][3]);
    float sn = fmaf(fg, syn[b], ig * gg);
    float rst = (mem[b] > thr2) ? thr2 : 0.0f;
    float mn = fmaf(og, tanh_fast(sn), -rst);
    float sf = (mn > thr2) ? 1.0f : 0.0f;
    p0[b] = fmaf(sf, wA0, p0[b]);
    p1[b] = fmaf(sf, wA1, p1[b]);
    p0[b] = fmaf(mn, wB0, p0[b]);
    p1[b] = fmaf(mn, wB1, p1[b]);
  }
  // cross-lane reduce; wsum result is uniform, keep own lane's value.
  float vout = 0.0f;
#pragma unroll
  for (int b = 0; b < NB; b++) {
    float r0 = wsum(p0[b]);
    float r1 = wsum(p1[b]);
    if (lane == 2 * b) vout = r0;
    if (lane == 2 * b + 1) vout = r1;
  }
  if (lane < 2 * NB)
    out[(size_t)wb * 2 + lane] = vout + ((lane & 1) ? bo1 : bo0);
}

extern "C" void kernel_launch(void* const* d_in, const int* in_sizes, int n_in,
                              void* d_out, int out_size, void* d_ws, size_t ws_size,
                              hipStream_t stream) {
  const float* x = (const float*)d_in[0];
  const float* Wih1 = (const float*)d_in[1];
  const float* Whh1 = (const float*)d_in[2];
  const float* bih1 = (const float*)d_in[3];
  const float* bhh1 = (const float*)d_in[4];
  const float* thr1 = (const float*)d_in[5];
  const float* Wih2 = (const float*)d_in[6];
  const float* Whh2 = (const float*)d_in[7];
  const float* bih2 = (const float*)d_in[8];
  const float* bhh2 = (const float*)d_in[9];
  const float* thr2 = (const float*)d_in[10];
  const float* Wout = (const float*)d_in[11];
  const float* bout = (const float*)d_in[12];

  unsigned long long* spk = (unsigned long long*)d_ws;
  float* mem1 = (float*)((char*)d_ws + (size_t)TT * BB * 8);

  snn_pass1<<<BB / (8 * NB), 512, 0, stream>>>(x, Wih1, Whh1, bih1, bhh1, thr1,
                                               spk, mem1);
  snn_pass2<<<BB / (16 * NB), 1024, 0, stream>>>(Wih2, Whh2, bih2, bhh2, thr2,
                                                 Wout, bout, spk, mem1,
                                                 (float*)d_out);
}